// Round 1
// baseline (247.013 us; speedup 1.0000x reference)
//
#include <hip/hip_runtime.h>

#define NPTS 32768
#define BLOCK 256
#define SPT 2                         // source points per thread
#define NSLICE 4                      // target slices (per direction)
#define SLICE_PTS (NPTS / NSLICE)     // 8192
#define TILE 2048                     // targets staged in LDS per tile (32 KB)
#define SRC_PER_BLOCK (BLOCK * SPT)   // 512
#define SRC_CHUNKS (NPTS / SRC_PER_BLOCK) // 64

// Pass 1: each block = (dir, source-chunk of 512, target-slice of 8192).
// Inner loop per pair: 3 v_fma_f32 + 1 v_max_f32 using
//   min_t |s-t|^2 = |s|^2 - 2 * max_t (s.t - |t|^2/2)
__global__ __launch_bounds__(BLOCK, 2)
void chamfer_pass1(const float* __restrict__ pred,
                   const float* __restrict__ targ,
                   unsigned int* __restrict__ mins) {
    __shared__ float4 sh[TILE];

    int b = blockIdx.x;
    int dir = b >> 8;            // 0: pred->target, 1: target->pred
    int rem = b & 255;
    int slice = rem >> 6;        // 0..3
    int chunk = rem & 63;        // 0..63

    const float* src = dir ? targ : pred;
    const float* tgt = dir ? pred : targ;
    unsigned int* outm = mins + dir * NPTS;

    int i0 = chunk * SRC_PER_BLOCK + threadIdx.x;
    int i1 = i0 + BLOCK;
    float s0x = src[3*i0+0], s0y = src[3*i0+1], s0z = src[3*i0+2];
    float s1x = src[3*i1+0], s1y = src[3*i1+1], s1z = src[3*i1+2];
    float m0 = -3.4e38f, m1 = -3.4e38f;

    int slice_base = slice * SLICE_PTS;
    for (int tb = 0; tb < SLICE_PTS; tb += TILE) {
        // stage TILE targets into LDS as {x, y, z, -|t|^2/2}
        #pragma unroll
        for (int k = 0; k < TILE / BLOCK; ++k) {
            int j = threadIdx.x + k * BLOCK;
            int g = slice_base + tb + j;
            float x = tgt[3*g+0], y = tgt[3*g+1], z = tgt[3*g+2];
            float qh = -0.5f * (x*x + y*y + z*z);
            sh[j] = make_float4(x, y, z, qh);
        }
        __syncthreads();
        #pragma unroll 8
        for (int j = 0; j < TILE; ++j) {
            float4 t = sh[j];   // broadcast ds_read_b128 (all lanes same addr)
            float r0 = fmaf(s0x, t.x, fmaf(s0y, t.y, fmaf(s0z, t.z, t.w)));
            float r1 = fmaf(s1x, t.x, fmaf(s1y, t.y, fmaf(s1z, t.z, t.w)));
            m0 = fmaxf(m0, r0);
            m1 = fmaxf(m1, r1);
        }
        __syncthreads();
    }

    float q0 = s0x*s0x + s0y*s0y + s0z*s0z;
    float q1 = s1x*s1x + s1y*s1y + s1z*s1z;
    float d0 = fmaxf(fmaf(-2.0f, m0, q0), 0.0f);  // non-negative by construction
    float d1 = fmaxf(fmaf(-2.0f, m1, q1), 0.0f);
    // non-negative float: uint compare == float compare
    atomicMin(&outm[i0], __float_as_uint(d0));
    atomicMin(&outm[i1], __float_as_uint(d1));
}

// Pass 2: sum all 65536 per-point mins; out = sum / 32768 (= mean1 + mean2).
__global__ __launch_bounds__(256)
void chamfer_pass2(const unsigned int* __restrict__ mins,
                   float* __restrict__ out) {
    float sum = 0.0f;
    for (int i = blockIdx.x * blockDim.x + threadIdx.x; i < 2 * NPTS;
         i += gridDim.x * blockDim.x)
        sum += __uint_as_float(mins[i]);
    #pragma unroll
    for (int off = 32; off > 0; off >>= 1)
        sum += __shfl_down(sum, off, 64);
    __shared__ float wsum[4];
    int lane = threadIdx.x & 63, wave = threadIdx.x >> 6;
    if (lane == 0) wsum[wave] = sum;
    __syncthreads();
    if (threadIdx.x == 0) {
        float s = wsum[0] + wsum[1] + wsum[2] + wsum[3];
        atomicAdd(out, s * (1.0f / NPTS));
    }
}

extern "C" void kernel_launch(void* const* d_in, const int* in_sizes, int n_in,
                              void* d_out, int out_size, void* d_ws, size_t ws_size,
                              hipStream_t stream) {
    const float* pred = (const float*)d_in[0];
    const float* targ = (const float*)d_in[1];
    float* out = (float*)d_out;
    unsigned int* mins = (unsigned int*)d_ws;

    // sentinel 0x7F7F7F7F == 3.39e38f in every ws float
    hipMemsetAsync(d_ws, 0x7F, 2 * NPTS * sizeof(float), stream);
    hipMemsetAsync(d_out, 0, sizeof(float), stream);

    chamfer_pass1<<<2 * SRC_CHUNKS * NSLICE, BLOCK, 0, stream>>>(pred, targ, mins);
    chamfer_pass2<<<64, 256, 0, stream>>>(mins, out);
}

// Round 2
// 226.386 us; speedup vs baseline: 1.0911x; 1.0911x over previous
//
#include <hip/hip_runtime.h>

#define NPTS 32768
#define BLOCK 256
#define SPT 8                           // source points per thread
#define NSLICE 16                       // target slices per direction
#define SLICE_PTS (NPTS / NSLICE)       // 2048
#define TILE SLICE_PTS                  // whole slice staged once (32 KB LDS)
#define SRC_PER_BLOCK (BLOCK * SPT)     // 2048
#define SRC_CHUNKS (NPTS / SRC_PER_BLOCK) // 16

// Pass 1: block = (dir, source-chunk of 2048, target-slice of 2048).
// min_t |s-t|^2 = |s|^2 - 2 * max_t (s.t - |t|^2/2); qh = -|t|^2/2 staged in LDS.
// Inner: 2 targets per step -> 6 v_fma_f32 + 1 v_max3_f32 per source point.
__global__ __launch_bounds__(BLOCK, 2)
void chamfer_pass1(const float* __restrict__ pred,
                   const float* __restrict__ targ,
                   unsigned int* __restrict__ mins) {
    __shared__ float4 sh[TILE];

    int b = blockIdx.x;
    int dir = b >> 8;              // 0: pred->target, 1: target->pred
    int rem = b & 255;
    int slice = rem >> 4;          // 0..15
    int chunk = rem & 15;          // 0..15

    const float* src = dir ? targ : pred;
    const float* tgt = dir ? pred : targ;
    unsigned int* outm = mins + dir * NPTS;

    // stage the target slice as {x, y, z, -|t|^2/2}
    int slice_base = slice * SLICE_PTS;
    #pragma unroll
    for (int k = 0; k < TILE / BLOCK; ++k) {
        int j = threadIdx.x + k * BLOCK;
        int g = slice_base + j;
        float x = tgt[3*g+0], y = tgt[3*g+1], z = tgt[3*g+2];
        sh[j] = make_float4(x, y, z, -0.5f * (x*x + y*y + z*z));
    }

    // load 8 source points into registers
    float sx[SPT], sy[SPT], sz[SPT], m[SPT];
    int i_base = chunk * SRC_PER_BLOCK + threadIdx.x;
    #pragma unroll
    for (int p = 0; p < SPT; ++p) {
        int i = i_base + p * BLOCK;
        sx[p] = src[3*i+0]; sy[p] = src[3*i+1]; sz[p] = src[3*i+2];
        m[p] = -3.4e38f;
    }
    __syncthreads();

    #pragma unroll 4
    for (int j = 0; j < TILE; j += 2) {
        float4 ta = sh[j];
        float4 tb = sh[j+1];
        #pragma unroll
        for (int p = 0; p < SPT; ++p) {
            float ra = fmaf(sx[p], ta.x, fmaf(sy[p], ta.y, fmaf(sz[p], ta.z, ta.w)));
            float rb = fmaf(sx[p], tb.x, fmaf(sy[p], tb.y, fmaf(sz[p], tb.z, tb.w)));
            m[p] = fmaxf(m[p], fmaxf(ra, rb));   // -> v_max3_f32
        }
    }

    #pragma unroll
    for (int p = 0; p < SPT; ++p) {
        int i = i_base + p * BLOCK;
        float q = fmaf(sx[p], sx[p], fmaf(sy[p], sy[p], sz[p]*sz[p]));
        float d = fmaxf(fmaf(-2.0f, m[p], q), 0.0f);  // exact distance >= 0
        atomicMin(&outm[i], __float_as_uint(d));      // non-neg float: uint cmp ok
    }
}

// Pass 2: sum all 65536 per-point mins; out = sum / 32768 (= mean1 + mean2).
__global__ __launch_bounds__(256)
void chamfer_pass2(const unsigned int* __restrict__ mins,
                   float* __restrict__ out) {
    float sum = 0.0f;
    for (int i = blockIdx.x * blockDim.x + threadIdx.x; i < 2 * NPTS;
         i += gridDim.x * blockDim.x)
        sum += __uint_as_float(mins[i]);
    #pragma unroll
    for (int off = 32; off > 0; off >>= 1)
        sum += __shfl_down(sum, off, 64);
    __shared__ float wsum[4];
    int lane = threadIdx.x & 63, wave = threadIdx.x >> 6;
    if (lane == 0) wsum[wave] = sum;
    __syncthreads();
    if (threadIdx.x == 0) {
        float s = wsum[0] + wsum[1] + wsum[2] + wsum[3];
        atomicAdd(out, s * (1.0f / NPTS));
    }
}

extern "C" void kernel_launch(void* const* d_in, const int* in_sizes, int n_in,
                              void* d_out, int out_size, void* d_ws, size_t ws_size,
                              hipStream_t stream) {
    const float* pred = (const float*)d_in[0];
    const float* targ = (const float*)d_in[1];
    float* out = (float*)d_out;
    unsigned int* mins = (unsigned int*)d_ws;

    // sentinel 0x7F7F7F7F == 3.39e38f in every ws float
    hipMemsetAsync(d_ws, 0x7F, 2 * NPTS * sizeof(float), stream);
    hipMemsetAsync(d_out, 0, sizeof(float), stream);

    chamfer_pass1<<<2 * SRC_CHUNKS * NSLICE, BLOCK, 0, stream>>>(pred, targ, mins);
    chamfer_pass2<<<64, 256, 0, stream>>>(mins, out);
}